// Round 1
// baseline (3321.031 us; speedup 1.0000x reference)
//
#include <hip/hip_runtime.h>
#include <hip/hip_bf16.h>

// TinyTransformerBlock: B=4, S=2048, D=1024, DFF=4096, fp32.
// Round 0: correct fp32 baseline. Tiled vector-ALU GEMMs (no fp32 MFMA on CDNA4).
//
// Pipeline:
//   q = x@wq, k = x@wk, v = x@wv                 (GEMM NN, 8192x1024x1024 each)
//   s[b] = q[b] @ k[b]^T                         (GEMM NT, batched z=4, 2048x2048x1024)
//   s = softmax(s, axis=-1)                      (row softmax, 8192 rows x 2048)
//   attn[b] = s[b] @ v[b]                        (GEMM NN batched, 2048x1024x2048)
//   proj = attn @ wo                             (GEMM NN)
//   hidden = relu(proj @ w1)                     (GEMM NN + relu, N=4096)
//   out = hidden @ w2 + x                        (GEMM NN + residual)
//
// Workspace (floats): [k: 8M][q: 8M][v: 8M][scores: 16M]  = 40M floats = 160 MB
//   attn  -> q region (reads s,v only)
//   proj  -> k region (reads attn=q region)
//   hidden (32M floats) -> q+v+s regions contiguous (reads proj=k region)

#define BM 128
#define BN 128
#define BK 16

// MODE: 0 = NN (B is [K,N] row-major), 1 = NT (B is [N,K] row-major)
// EPI:  0 = none, 1 = relu, 2 = add residual R
template<int MODE, int EPI>
__global__ __launch_bounds__(256)
void gemm_f32(const float* __restrict__ A, const float* __restrict__ B,
              const float* __restrict__ R, float* __restrict__ C,
              int M, int N, int K,
              long long sA, long long sB, long long sC)
{
    __shared__ float As[BK][BM + 4];
    __shared__ float Bs[BK][BN + 4];

    const int t = threadIdx.x;
    const int z = blockIdx.z;
    A += (long long)z * sA;
    B += (long long)z * sB;
    C += (long long)z * sC;
    if (EPI == 2) R += (long long)z * sC;

    const int bm0 = blockIdx.y * BM;
    const int bn0 = blockIdx.x * BN;

    // A/NT-B staging indices: 2 x float4 per thread, transposed into LDS
    const int arow = t >> 2;          // 0..63
    const int akc  = (t & 3) << 2;    // 0,4,8,12
    // NN-B staging indices: 2 x float4 per thread, direct
    const int bkr = t >> 5;           // 0..7
    const int bnc = (t & 31) << 2;    // 0..124
    // compute mapping: 8x8 micro-tile per thread
    const int ty = t >> 4;            // 0..15
    const int tx = t & 15;            // 0..15

    float acc[8][8] = {};

    for (int k0 = 0; k0 < K; k0 += BK) {
        float4 a0 = *(const float4*)(A + (size_t)(bm0 + arow) * K + (k0 + akc));
        float4 a1 = *(const float4*)(A + (size_t)(bm0 + arow + 64) * K + (k0 + akc));
        float4 b0, b1;
        if (MODE == 0) {
            b0 = *(const float4*)(B + (size_t)(k0 + bkr) * N + (bn0 + bnc));
            b1 = *(const float4*)(B + (size_t)(k0 + bkr + 8) * N + (bn0 + bnc));
        } else {
            b0 = *(const float4*)(B + (size_t)(bn0 + arow) * K + (k0 + akc));
            b1 = *(const float4*)(B + (size_t)(bn0 + arow + 64) * K + (k0 + akc));
        }

        __syncthreads();   // previous iteration's LDS reads complete

        As[akc + 0][arow] = a0.x;
        As[akc + 1][arow] = a0.y;
        As[akc + 2][arow] = a0.z;
        As[akc + 3][arow] = a0.w;
        As[akc + 0][arow + 64] = a1.x;
        As[akc + 1][arow + 64] = a1.y;
        As[akc + 2][arow + 64] = a1.z;
        As[akc + 3][arow + 64] = a1.w;
        if (MODE == 0) {
            *(float4*)&Bs[bkr][bnc]     = b0;
            *(float4*)&Bs[bkr + 8][bnc] = b1;
        } else {
            Bs[akc + 0][arow] = b0.x;
            Bs[akc + 1][arow] = b0.y;
            Bs[akc + 2][arow] = b0.z;
            Bs[akc + 3][arow] = b0.w;
            Bs[akc + 0][arow + 64] = b1.x;
            Bs[akc + 1][arow + 64] = b1.y;
            Bs[akc + 2][arow + 64] = b1.z;
            Bs[akc + 3][arow + 64] = b1.w;
        }

        __syncthreads();

        #pragma unroll
        for (int kk = 0; kk < BK; ++kk) {
            float a[8], b[8];
            *(float4*)&a[0] = *(const float4*)&As[kk][ty * 8];
            *(float4*)&a[4] = *(const float4*)&As[kk][ty * 8 + 4];
            *(float4*)&b[0] = *(const float4*)&Bs[kk][tx * 8];
            *(float4*)&b[4] = *(const float4*)&Bs[kk][tx * 8 + 4];
            #pragma unroll
            for (int i = 0; i < 8; ++i)
                #pragma unroll
                for (int j = 0; j < 8; ++j)
                    acc[i][j] = fmaf(a[i], b[j], acc[i][j]);
        }
    }

    #pragma unroll
    for (int i = 0; i < 8; ++i) {
        const size_t row = (size_t)(bm0 + ty * 8 + i);
        float* cp = C + row * N + (bn0 + tx * 8);
        float v[8];
        #pragma unroll
        for (int j = 0; j < 8; ++j) v[j] = acc[i][j];
        if (EPI == 1) {
            #pragma unroll
            for (int j = 0; j < 8; ++j) v[j] = fmaxf(v[j], 0.0f);
        }
        if (EPI == 2) {
            const float* rp = R + row * N + (bn0 + tx * 8);
            float4 r0 = *(const float4*)(rp);
            float4 r1 = *(const float4*)(rp + 4);
            v[0] += r0.x; v[1] += r0.y; v[2] += r0.z; v[3] += r0.w;
            v[4] += r1.x; v[5] += r1.y; v[6] += r1.z; v[7] += r1.w;
        }
        float4 o0 = make_float4(v[0], v[1], v[2], v[3]);
        float4 o1 = make_float4(v[4], v[5], v[6], v[7]);
        *(float4*)(cp)     = o0;
        *(float4*)(cp + 4) = o1;
    }
}

// Row softmax over 2048 columns; one block (256 threads) per row, 8 elems/thread.
__global__ __launch_bounds__(256)
void softmax2048(float* __restrict__ S)
{
    __shared__ float red[256];
    float* p = S + (size_t)blockIdx.x * 2048;
    const int t = threadIdx.x;

    float4 u0 = *(float4*)(p + t * 4);
    float4 u1 = *(float4*)(p + 1024 + t * 4);

    float m = fmaxf(fmaxf(fmaxf(u0.x, u0.y), fmaxf(u0.z, u0.w)),
                    fmaxf(fmaxf(u1.x, u1.y), fmaxf(u1.z, u1.w)));
    red[t] = m;
    __syncthreads();
    #pragma unroll
    for (int s = 128; s > 0; s >>= 1) {
        if (t < s) red[t] = fmaxf(red[t], red[t + s]);
        __syncthreads();
    }
    const float rowmax = red[0];
    __syncthreads();

    u0.x = __expf(u0.x - rowmax); u0.y = __expf(u0.y - rowmax);
    u0.z = __expf(u0.z - rowmax); u0.w = __expf(u0.w - rowmax);
    u1.x = __expf(u1.x - rowmax); u1.y = __expf(u1.y - rowmax);
    u1.z = __expf(u1.z - rowmax); u1.w = __expf(u1.w - rowmax);

    float sum = (u0.x + u0.y + u0.z + u0.w) + (u1.x + u1.y + u1.z + u1.w);
    red[t] = sum;
    __syncthreads();
    #pragma unroll
    for (int s = 128; s > 0; s >>= 1) {
        if (t < s) red[t] += red[t + s];
        __syncthreads();
    }
    const float inv = 1.0f / red[0];

    u0.x *= inv; u0.y *= inv; u0.z *= inv; u0.w *= inv;
    u1.x *= inv; u1.y *= inv; u1.z *= inv; u1.w *= inv;
    *(float4*)(p + t * 4)        = u0;
    *(float4*)(p + 1024 + t * 4) = u1;
}

extern "C" void kernel_launch(void* const* d_in, const int* in_sizes, int n_in,
                              void* d_out, int out_size, void* d_ws, size_t ws_size,
                              hipStream_t stream)
{
    const float* x  = (const float*)d_in[0];
    const float* wq = (const float*)d_in[1];
    const float* wk = (const float*)d_in[2];
    const float* wv = (const float*)d_in[3];
    const float* wo = (const float*)d_in[4];
    const float* w1 = (const float*)d_in[5];
    const float* w2 = (const float*)d_in[6];
    float* out = (float*)d_out;

    const int Bb = 4, S = 2048, D = 1024, DFF = 4096;
    const int NTOK = Bb * S;                 // 8192
    const long long sQKV = (long long)S * D; // per-batch stride in q/k/v
    const long long sSS  = (long long)S * S; // per-batch stride in scores

    float* W    = (float*)d_ws;
    float* kbuf = W;                         // 8M floats
    float* qbuf = W + (size_t)NTOK * D;      // 8M floats
    float* vbuf = W + 2 * (size_t)NTOK * D;  // 8M floats
    float* sbuf = W + 3 * (size_t)NTOK * D;  // 16M floats
    float* attn = qbuf;                      // overwrites q (q unused after scores)
    float* proj = kbuf;                      // overwrites k
    float* hid  = qbuf;                      // 32M floats over q+v+s regions

    dim3 blk(256);

    // q, k, v projections
    gemm_f32<0,0><<<dim3(D / BN, NTOK / BM, 1), blk, 0, stream>>>(x, wq, nullptr, qbuf, NTOK, D, D, 0, 0, 0);
    gemm_f32<0,0><<<dim3(D / BN, NTOK / BM, 1), blk, 0, stream>>>(x, wk, nullptr, kbuf, NTOK, D, D, 0, 0, 0);
    gemm_f32<0,0><<<dim3(D / BN, NTOK / BM, 1), blk, 0, stream>>>(x, wv, nullptr, vbuf, NTOK, D, D, 0, 0, 0);

    // scores[b] = q[b] @ k[b]^T   (batched NT)
    gemm_f32<1,0><<<dim3(S / BN, S / BM, Bb), blk, 0, stream>>>(qbuf, kbuf, nullptr, sbuf, S, S, D, sQKV, sQKV, sSS);

    // softmax rows
    softmax2048<<<dim3(NTOK), blk, 0, stream>>>(sbuf);

    // attn[b] = weights[b] @ v[b]   (batched NN)
    gemm_f32<0,0><<<dim3(D / BN, S / BM, Bb), blk, 0, stream>>>(sbuf, vbuf, nullptr, attn, S, D, S, sSS, sQKV, sQKV);

    // proj = attn @ wo
    gemm_f32<0,0><<<dim3(D / BN, NTOK / BM, 1), blk, 0, stream>>>(attn, wo, nullptr, proj, NTOK, D, D, 0, 0, 0);

    // hidden = relu(proj @ w1)
    gemm_f32<0,1><<<dim3(DFF / BN, NTOK / BM, 1), blk, 0, stream>>>(proj, w1, nullptr, hid, NTOK, DFF, D, 0, 0, 0);

    // out = hidden @ w2 + x
    gemm_f32<0,2><<<dim3(D / BN, NTOK / BM, 1), blk, 0, stream>>>(hid, w2, x, out, NTOK, D, DFF, 0, 0, 0);
}

// Round 2
// 540.661 us; speedup vs baseline: 6.1425x; 6.1425x over previous
//
#include <hip/hip_runtime.h>
#include <hip/hip_bf16.h>
#include <hip/hip_fp16.h>

// TinyTransformerBlock: B=4, S=2048, D=1024, DFF=4096, fp32 in/out.
// R2: all GEMMs on MFMA f16 (16x16x32), m97-style 128x128x32 tiles with
// global_load_lds width-16 staging. Scores kept fp32; softmax casts to fp16.
//
// All GEMMs are NT: C[M][N] = A[M][K] * Bt[N][K]^T.
//   q  = xh @ wqT'     k = xh @ wkT'     vT = wvT @ xh'   (vT directly [D][T])
//   s  = qh @ kh'  (batched, fp32 out)
//   p  = softmax(s) -> fp16
//   at = p @ vT'   (batched)     proj = at @ woT'
//   hid= relu(proj @ w1T')       out  = hid @ w2T' + x  (fp32)

typedef _Float16 f16;
typedef __attribute__((ext_vector_type(8))) _Float16 f16x8;
typedef __attribute__((ext_vector_type(4))) _Float16 f16x4;
typedef __attribute__((ext_vector_type(4))) float f32x4;

#define BM 128
#define BN 128
#define BK 32

__device__ inline void gload16(const void* g, void* l) {
    __builtin_amdgcn_global_load_lds(
        (const __attribute__((address_space(1))) void*)g,
        (__attribute__((address_space(3))) void*)l, 16, 0, 0);
}

// EPI: 0 = f16 store, 1 = f16 relu store, 2 = f32 store, 3 = f32 + residual
template<int EPI>
__global__ __launch_bounds__(256)
void gemm_f16(const f16* __restrict__ A, const f16* __restrict__ Bt,
              const float* __restrict__ Res, void* __restrict__ Cv,
              int K, int lda, int ldb, int ldc,
              long long sA, long long sB, long long sC)
{
    __shared__ f16 Ash[BM * BK];   // 8 KB, unpadded (global_load_lds contiguity)
    __shared__ f16 Bsh[BN * BK];   // 8 KB

    const int t = threadIdx.x;
    const int z = blockIdx.z;
    A  += (size_t)z * sA;
    Bt += (size_t)z * sB;

    const int bm0 = blockIdx.y * BM;
    const int bn0 = blockIdx.x * BN;

    const int lane = t & 63;
    const int wid  = t >> 6;            // wave 0..3
    const int quad = lane >> 4;
    const int m16  = lane & 15;
    const int wm = (wid & 1) * 64;
    const int wn = (wid >> 1) * 64;

    // staging: chunk c (c = t for load0, t+256 for load1) covers LDS bytes
    // [c*16, c*16+16) = tile row c/4, k-col (c%4)*8
    const int r0 = t >> 2;              // 0..63
    const int kc = (t & 3) * 8;
    const char* gA0 = (const char*)(A  + (size_t)(bm0 + r0)      * lda + kc);
    const char* gA1 = (const char*)(A  + (size_t)(bm0 + 64 + r0) * lda + kc);
    const char* gB0 = (const char*)(Bt + (size_t)(bn0 + r0)      * ldb + kc);
    const char* gB1 = (const char*)(Bt + (size_t)(bn0 + 64 + r0) * ldb + kc);
    char* lA = (char*)Ash;
    char* lB = (char*)Bsh;
    const int wbase = wid << 10;        // per-wave 1024B segment

    f32x4 acc[4][4] = {};

    const int nk = K / BK;
    // issue tile kt (global byte offset kt*BK*2 = kt*64)
    #define ISSUE(kt) do { int ko = (kt) * 64;          \
        gload16(gA0 + ko, lA + wbase);                  \
        gload16(gA1 + ko, lA + 4096 + wbase);           \
        gload16(gB0 + ko, lB + wbase);                  \
        gload16(gB1 + ko, lB + 4096 + wbase); } while (0)

    ISSUE(0);
    for (int kt = 0; kt < nk; ++kt) {
        __syncthreads();                       // tile kt resident (vmcnt drained)
        f16x8 af[4], bf[4];
        #pragma unroll
        for (int i = 0; i < 4; ++i) {
            af[i] = *(const f16x8*)&Ash[(wm + i * 16 + m16) * BK + quad * 8];
            bf[i] = *(const f16x8*)&Bsh[(wn + i * 16 + m16) * BK + quad * 8];
        }
        __syncthreads();                       // all waves' ds_reads done
        if (kt + 1 < nk) ISSUE(kt + 1);        // prefetch overlaps MFMA
        #pragma unroll
        for (int i = 0; i < 4; ++i)
            #pragma unroll
            for (int j = 0; j < 4; ++j)
                acc[i][j] = __builtin_amdgcn_mfma_f32_16x16x32_f16(
                                af[i], bf[j], acc[i][j], 0, 0, 0);
    }
    #undef ISSUE

    // C/D layout: col = lane&15, row = quad*4 + reg
    if (EPI <= 1) {
        f16* C = (f16*)Cv + (size_t)z * sC;
        #pragma unroll
        for (int i = 0; i < 4; ++i)
            #pragma unroll
            for (int ri = 0; ri < 4; ++ri) {
                const size_t row = (size_t)(bm0 + wm + i * 16 + quad * 4 + ri);
                f16* cp = C + row * ldc + (bn0 + wn + m16);
                #pragma unroll
                for (int j = 0; j < 4; ++j) {
                    float v = acc[i][j][ri];
                    if (EPI == 1) v = fmaxf(v, 0.0f);
                    cp[j * 16] = (f16)v;
                }
            }
    } else {
        float* C = (float*)Cv + (size_t)z * sC;
        #pragma unroll
        for (int i = 0; i < 4; ++i)
            #pragma unroll
            for (int ri = 0; ri < 4; ++ri) {
                const size_t row = (size_t)(bm0 + wm + i * 16 + quad * 4 + ri);
                float* cp = C + row * ldc + (bn0 + wn + m16);
                const float* rp = (EPI == 3) ? Res + row * ldc + (bn0 + wn + m16)
                                             : nullptr;
                #pragma unroll
                for (int j = 0; j < 4; ++j) {
                    float v = acc[i][j][ri];
                    if (EPI == 3) v += rp[j * 16];
                    cp[j * 16] = v;
                }
            }
    }
}

// fp32 [R][C] -> fp16 [C][R]
__global__ __launch_bounds__(256)
void transpose_cast(const float* __restrict__ in, f16* __restrict__ out,
                    int R, int C)
{
    __shared__ float tile[64][65];
    const int c0 = blockIdx.x * 64, r0 = blockIdx.y * 64;
    const int tc = threadIdx.x & 63, tr = threadIdx.x >> 6;   // tr 0..3
    #pragma unroll
    for (int i = 0; i < 16; ++i)
        tile[tr + i * 4][tc] = in[(size_t)(r0 + tr + i * 4) * C + c0 + tc];
    __syncthreads();
    #pragma unroll
    for (int i = 0; i < 16; ++i)
        out[(size_t)(c0 + tr + i * 4) * R + r0 + tc] = (f16)tile[tc][tr + i * 4];
}

__global__ __launch_bounds__(256)
void cast_f16(const float* __restrict__ in, f16* __restrict__ out)
{
    const size_t i = ((size_t)blockIdx.x * 256 + threadIdx.x) * 4;
    float4 v = *(const float4*)(in + i);
    f16x4 o; o.x = (f16)v.x; o.y = (f16)v.y; o.z = (f16)v.z; o.w = (f16)v.w;
    *(f16x4*)(out + i) = o;
}

// row softmax over 2048 fp32 -> fp16
__global__ __launch_bounds__(256)
void softmax_f16(const float* __restrict__ S, f16* __restrict__ P)
{
    __shared__ float red[256];
    const float* p = S + (size_t)blockIdx.x * 2048;
    f16* q = P + (size_t)blockIdx.x * 2048;
    const int t = threadIdx.x;

    float4 u0 = *(const float4*)(p + t * 4);
    float4 u1 = *(const float4*)(p + 1024 + t * 4);

    float m = fmaxf(fmaxf(fmaxf(u0.x, u0.y), fmaxf(u0.z, u0.w)),
                    fmaxf(fmaxf(u1.x, u1.y), fmaxf(u1.z, u1.w)));
    red[t] = m;
    __syncthreads();
    #pragma unroll
    for (int s = 128; s > 0; s >>= 1) {
        if (t < s) red[t] = fmaxf(red[t], red[t + s]);
        __syncthreads();
    }
    const float rowmax = red[0];
    __syncthreads();

    u0.x = __expf(u0.x - rowmax); u0.y = __expf(u0.y - rowmax);
    u0.z = __expf(u0.z - rowmax); u0.w = __expf(u0.w - rowmax);
    u1.x = __expf(u1.x - rowmax); u1.y = __expf(u1.y - rowmax);
    u1.z = __expf(u1.z - rowmax); u1.w = __expf(u1.w - rowmax);

    red[t] = (u0.x + u0.y + u0.z + u0.w) + (u1.x + u1.y + u1.z + u1.w);
    __syncthreads();
    #pragma unroll
    for (int s = 128; s > 0; s >>= 1) {
        if (t < s) red[t] += red[t + s];
        __syncthreads();
    }
    const float inv = 1.0f / red[0];

    f16x4 o0, o1;
    o0.x = (f16)(u0.x * inv); o0.y = (f16)(u0.y * inv);
    o0.z = (f16)(u0.z * inv); o0.w = (f16)(u0.w * inv);
    o1.x = (f16)(u1.x * inv); o1.y = (f16)(u1.y * inv);
    o1.z = (f16)(u1.z * inv); o1.w = (f16)(u1.w * inv);
    *(f16x4*)(q + t * 4)        = o0;
    *(f16x4*)(q + 1024 + t * 4) = o1;
}

extern "C" void kernel_launch(void* const* d_in, const int* in_sizes, int n_in,
                              void* d_out, int out_size, void* d_ws, size_t ws_size,
                              hipStream_t stream)
{
    const float* x  = (const float*)d_in[0];
    const float* wq = (const float*)d_in[1];
    const float* wk = (const float*)d_in[2];
    const float* wv = (const float*)d_in[3];
    const float* wo = (const float*)d_in[4];
    const float* w1 = (const float*)d_in[5];
    const float* w2 = (const float*)d_in[6];
    float* out = (float*)d_out;

    const int S = 2048, D = 1024, DFF = 4096, Bb = 4;
    const int NTOK = Bb * S;  // 8192

    // workspace layout (f16 elems unless noted); total 159.4 MB
    f16* W    = (f16*)d_ws;
    f16* xh   = W;                         // 8M
    f16* wqT  = xh  + (size_t)NTOK * D;    // 1M each
    f16* wkT  = wqT + (size_t)D * D;
    f16* wvT  = wkT + (size_t)D * D;
    f16* woT  = wvT + (size_t)D * D;
    f16* w1T  = woT + (size_t)D * D;       // 4M
    f16* w2T  = w1T + (size_t)D * DFF;     // 4M
    f16* qh   = w2T + (size_t)DFF * D;     // 8M
    f16* kh   = qh  + (size_t)NTOK * D;    // 8M
    f16* vT   = kh  + (size_t)NTOK * D;    // 8M  ([D][NTOK])
    float* sb = (float*)(vT + (size_t)D * NTOK);  // 16M fp32 (67 MB)
    f16* ph   = qh;                        // probs reuse q+k region (16M)
    f16* at   = xh;                        // attn reuses xh
    f16* pj   = vT;                        // proj reuses vT
    f16* hd   = (f16*)sb;                  // hidden reuses scores region

    dim3 blk(256);

    // casts / transposes
    cast_f16<<<dim3(NTOK * D / 1024), blk, 0, stream>>>(x, xh);
    transpose_cast<<<dim3(D / 64, D / 64), blk, 0, stream>>>(wq, wqT, D, D);
    transpose_cast<<<dim3(D / 64, D / 64), blk, 0, stream>>>(wk, wkT, D, D);
    transpose_cast<<<dim3(D / 64, D / 64), blk, 0, stream>>>(wv, wvT, D, D);
    transpose_cast<<<dim3(D / 64, D / 64), blk, 0, stream>>>(wo, woT, D, D);
    transpose_cast<<<dim3(DFF / 64, D / 64), blk, 0, stream>>>(w1, w1T, D, DFF);
    transpose_cast<<<dim3(D / 64, DFF / 64), blk, 0, stream>>>(w2, w2T, DFF, D);

    // q = xh @ wqT', k = xh @ wkT'   [8192][1024]
    gemm_f16<0><<<dim3(D / BN, NTOK / BM, 1), blk, 0, stream>>>(
        xh, wqT, nullptr, qh, D, D, D, D, 0, 0, 0);
    gemm_f16<0><<<dim3(D / BN, NTOK / BM, 1), blk, 0, stream>>>(
        xh, wkT, nullptr, kh, D, D, D, D, 0, 0, 0);
    // vT = wvT @ xh'   [1024][8192]
    gemm_f16<0><<<dim3(NTOK / BN, D / BM, 1), blk, 0, stream>>>(
        wvT, xh, nullptr, vT, D, D, D, NTOK, 0, 0, 0);

    // scores[b] = q_b @ k_b'  fp32 [2048][2048] x4
    gemm_f16<2><<<dim3(S / BN, S / BM, Bb), blk, 0, stream>>>(
        qh, kh, nullptr, sb, D, D, D, S,
        (long long)S * D, (long long)S * D, (long long)S * S);

    // softmax -> fp16 probs
    softmax_f16<<<dim3(NTOK), blk, 0, stream>>>(sb, ph);

    // attn[b] = p_b @ (vT_b)'   [2048][1024] x4   (vT batch = column slice)
    gemm_f16<0><<<dim3(D / BN, S / BM, Bb), blk, 0, stream>>>(
        ph, vT, nullptr, at, S, S, NTOK, D,
        (long long)S * S, (long long)S, (long long)S * D);

    // proj = at @ woT'
    gemm_f16<0><<<dim3(D / BN, NTOK / BM, 1), blk, 0, stream>>>(
        at, woT, nullptr, pj, D, D, D, D, 0, 0, 0);

    // hidden = relu(pj @ w1T')   [8192][4096]
    gemm_f16<1><<<dim3(DFF / BN, NTOK / BM, 1), blk, 0, stream>>>(
        pj, w1T, nullptr, hd, D, D, D, DFF, 0, 0, 0);

    // out = hd @ w2T' + x   fp32 [8192][1024]
    gemm_f16<3><<<dim3(D / BN, NTOK / BM, 1), blk, 0, stream>>>(
        hd, w2T, x, out, DFF, DFF, DFF, D, 0, 0, 0);
}

// Round 3
// 502.102 us; speedup vs baseline: 6.6143x; 1.0768x over previous
//
#include <hip/hip_runtime.h>
#include <hip/hip_bf16.h>
#include <hip/hip_fp16.h>

// TinyTransformerBlock: B=4, S=2048, D=1024, DFF=4096, fp32 in/out.
// R3: BK 32->64 (halve barrier-drain events), M-fastest grid (pin A row-tiles
// to one XCD -> cut redundant cross-XCD A fetches), merged q|k projection GEMM.
//
// All GEMMs NT: C[M][N] = A[M][K] * Bt[N][K]^T, f16 MFMA 16x16x32.
//   qk  = xh @ wqkT'  ([8192][2048]: q cols 0-1023, k cols 1024-2047)
//   vT  = wvT @ xh'   ([1024][8192])
//   s   = q @ k' (batched, fp32)   p = softmax(s) -> f16
//   at  = p @ vT'   proj = at @ woT'
//   hid = relu(proj @ w1T')   out = hid @ w2T' + x (fp32)

typedef _Float16 f16;
typedef __attribute__((ext_vector_type(8))) _Float16 f16x8;
typedef __attribute__((ext_vector_type(4))) _Float16 f16x4;
typedef __attribute__((ext_vector_type(4))) float f32x4;

#define BM 128
#define BN 128
#define BK 64

__device__ inline void gload16(const void* g, void* l) {
    __builtin_amdgcn_global_load_lds(
        (const __attribute__((address_space(1))) void*)g,
        (__attribute__((address_space(3))) void*)l, 16, 0, 0);
}

// EPI: 0 = f16 store, 1 = f16 relu store, 2 = f32 store, 3 = f32 + residual
// Grid: x = M-tile (fastest -> XCD-pinned A rows), y = N-tile, z = batch.
template<int EPI>
__global__ __launch_bounds__(256)
void gemm_f16(const f16* __restrict__ A, const f16* __restrict__ Bt,
              const float* __restrict__ Res, void* __restrict__ Cv,
              int K, int lda, int ldb, int ldc,
              long long sA, long long sB, long long sC)
{
    __shared__ f16 Ash[BM * BK];   // 16 KB, unpadded (global_load_lds layout)
    __shared__ f16 Bsh[BN * BK];   // 16 KB

    const int t = threadIdx.x;
    const int z = blockIdx.z;
    A  += (size_t)z * sA;
    Bt += (size_t)z * sB;

    const int bm0 = blockIdx.x * BM;   // M-tile fastest
    const int bn0 = blockIdx.y * BN;

    const int lane = t & 63;
    const int wid  = t >> 6;            // wave 0..3
    const int quad = lane >> 4;
    const int m16  = lane & 15;
    const int wm = (wid & 1) * 64;
    const int wn = (wid >> 1) * 64;

    // staging: 4 issues each for A and B; chunk c = i*256 + t covers LDS
    // bytes [c*16, c*16+16) = tile row c>>3 (row stride 128 B), k-col (c&7)*8 halves
    const int r0 = t >> 3;              // 0..31
    const int kc = (t & 7) * 8;         // half offset in row
    const char* gA[4]; const char* gB[4];
    #pragma unroll
    for (int i = 0; i < 4; ++i) {
        gA[i] = (const char*)(A  + (size_t)(bm0 + i * 32 + r0) * lda + kc);
        gB[i] = (const char*)(Bt + (size_t)(bn0 + i * 32 + r0) * ldb + kc);
    }
    char* lA = (char*)Ash + (wid << 10);   // wave-uniform base (+ lane*16 by HW)
    char* lB = (char*)Bsh + (wid << 10);

    f32x4 acc[4][4] = {};

    const int nk = K / BK;
    #define ISSUE(kt) do { const int ko = (kt) * 128;   \
        gload16(gA[0] + ko, lA);                        \
        gload16(gA[1] + ko, lA + 4096);                 \
        gload16(gA[2] + ko, lA + 8192);                 \
        gload16(gA[3] + ko, lA + 12288);                \
        gload16(gB[0] + ko, lB);                        \
        gload16(gB[1] + ko, lB + 4096);                 \
        gload16(gB[2] + ko, lB + 8192);                 \
        gload16(gB[3] + ko, lB + 12288); } while (0)

    ISSUE(0);
    for (int kt = 0; kt < nk; ++kt) {
        __syncthreads();                       // tile kt resident (vmcnt drained)
        f16x8 af[2][4], bf[2][4];
        #pragma unroll
        for (int s = 0; s < 2; ++s)
            #pragma unroll
            for (int i = 0; i < 4; ++i) {
                af[s][i] = *(const f16x8*)&Ash[(wm + i * 16 + m16) * BK + s * 32 + quad * 8];
                bf[s][i] = *(const f16x8*)&Bsh[(wn + i * 16 + m16) * BK + s * 32 + quad * 8];
            }
        __syncthreads();                       // all waves' ds_reads done
        if (kt + 1 < nk) ISSUE(kt + 1);        // prefetch overlaps MFMA
        #pragma unroll
        for (int s = 0; s < 2; ++s)
            #pragma unroll
            for (int i = 0; i < 4; ++i)
                #pragma unroll
                for (int j = 0; j < 4; ++j)
                    acc[i][j] = __builtin_amdgcn_mfma_f32_16x16x32_f16(
                                    af[s][i], bf[s][j], acc[i][j], 0, 0, 0);
    }
    #undef ISSUE

    // C/D layout: col = lane&15, row = quad*4 + reg
    if (EPI <= 1) {
        f16* C = (f16*)Cv + (size_t)z * sC;
        #pragma unroll
        for (int i = 0; i < 4; ++i)
            #pragma unroll
            for (int ri = 0; ri < 4; ++ri) {
                const size_t row = (size_t)(bm0 + wm + i * 16 + quad * 4 + ri);
                f16* cp = C + row * ldc + (bn0 + wn + m16);
                #pragma unroll
                for (int j = 0; j < 4; ++j) {
                    float v = acc[i][j][ri];
                    if (EPI == 1) v = fmaxf(v, 0.0f);
                    cp[j * 16] = (f16)v;
                }
            }
    } else {
        float* C = (float*)Cv + (size_t)z * sC;
        #pragma unroll
        for (int i = 0; i < 4; ++i)
            #pragma unroll
            for (int ri = 0; ri < 4; ++ri) {
                const size_t row = (size_t)(bm0 + wm + i * 16 + quad * 4 + ri);
                float* cp = C + row * ldc + (bn0 + wn + m16);
                const float* rp = (EPI == 3) ? Res + row * ldc + (bn0 + wn + m16)
                                             : nullptr;
                #pragma unroll
                for (int j = 0; j < 4; ++j) {
                    float v = acc[i][j][ri];
                    if (EPI == 3) v += rp[j * 16];
                    cp[j * 16] = v;
                }
            }
    }
}

// fp32 [R][C] -> fp16 [C][R]
__global__ __launch_bounds__(256)
void transpose_cast(const float* __restrict__ in, f16* __restrict__ out,
                    int R, int C)
{
    __shared__ float tile[64][65];
    const int c0 = blockIdx.x * 64, r0 = blockIdx.y * 64;
    const int tc = threadIdx.x & 63, tr = threadIdx.x >> 6;   // tr 0..3
    #pragma unroll
    for (int i = 0; i < 16; ++i)
        tile[tr + i * 4][tc] = in[(size_t)(r0 + tr + i * 4) * C + c0 + tc];
    __syncthreads();
    #pragma unroll
    for (int i = 0; i < 16; ++i)
        out[(size_t)(c0 + tr + i * 4) * R + r0 + tc] = (f16)tile[tc][tr + i * 4];
}

__global__ __launch_bounds__(256)
void cast_f16(const float* __restrict__ in, f16* __restrict__ out)
{
    const size_t i = ((size_t)blockIdx.x * 256 + threadIdx.x) * 4;
    float4 v = *(const float4*)(in + i);
    f16x4 o; o.x = (f16)v.x; o.y = (f16)v.y; o.z = (f16)v.z; o.w = (f16)v.w;
    *(f16x4*)(out + i) = o;
}

// row softmax over 2048 fp32 -> fp16
__global__ __launch_bounds__(256)
void softmax_f16(const float* __restrict__ S, f16* __restrict__ P)
{
    __shared__ float red[256];
    const float* p = S + (size_t)blockIdx.x * 2048;
    f16* q = P + (size_t)blockIdx.x * 2048;
    const int t = threadIdx.x;

    float4 u0 = *(const float4*)(p + t * 4);
    float4 u1 = *(const float4*)(p + 1024 + t * 4);

    float m = fmaxf(fmaxf(fmaxf(u0.x, u0.y), fmaxf(u0.z, u0.w)),
                    fmaxf(fmaxf(u1.x, u1.y), fmaxf(u1.z, u1.w)));
    red[t] = m;
    __syncthreads();
    #pragma unroll
    for (int s = 128; s > 0; s >>= 1) {
        if (t < s) red[t] = fmaxf(red[t], red[t + s]);
        __syncthreads();
    }
    const float rowmax = red[0];
    __syncthreads();

    u0.x = __expf(u0.x - rowmax); u0.y = __expf(u0.y - rowmax);
    u0.z = __expf(u0.z - rowmax); u0.w = __expf(u0.w - rowmax);
    u1.x = __expf(u1.x - rowmax); u1.y = __expf(u1.y - rowmax);
    u1.z = __expf(u1.z - rowmax); u1.w = __expf(u1.w - rowmax);

    red[t] = (u0.x + u0.y + u0.z + u0.w) + (u1.x + u1.y + u1.z + u1.w);
    __syncthreads();
    #pragma unroll
    for (int s = 128; s > 0; s >>= 1) {
        if (t < s) red[t] += red[t + s];
        __syncthreads();
    }
    const float inv = 1.0f / red[0];

    f16x4 o0, o1;
    o0.x = (f16)(u0.x * inv); o0.y = (f16)(u0.y * inv);
    o0.z = (f16)(u0.z * inv); o0.w = (f16)(u0.w * inv);
    o1.x = (f16)(u1.x * inv); o1.y = (f16)(u1.y * inv);
    o1.z = (f16)(u1.z * inv); o1.w = (f16)(u1.w * inv);
    *(f16x4*)(q + t * 4)        = o0;
    *(f16x4*)(q + 1024 + t * 4) = o1;
}

extern "C" void kernel_launch(void* const* d_in, const int* in_sizes, int n_in,
                              void* d_out, int out_size, void* d_ws, size_t ws_size,
                              hipStream_t stream)
{
    const float* x  = (const float*)d_in[0];
    const float* wq = (const float*)d_in[1];
    const float* wk = (const float*)d_in[2];
    const float* wv = (const float*)d_in[3];
    const float* wo = (const float*)d_in[4];
    const float* w1 = (const float*)d_in[5];
    const float* w2 = (const float*)d_in[6];
    float* out = (float*)d_out;

    const int S = 2048, D = 1024, DFF = 4096, Bb = 4;
    const int NTOK = Bb * S;  // 8192

    // workspace (halves unless noted); total 152 MB
    f16* W    = (f16*)d_ws;
    f16* xh   = W;                           // 8M
    f16* wqkT = xh   + (size_t)NTOK * D;     // 2M  ([2048][1024]: wqT | wkT)
    f16* wvT  = wqkT + (size_t)2 * D * D;    // 1M
    f16* woT  = wvT  + (size_t)D * D;        // 1M
    f16* w1T  = woT  + (size_t)D * D;        // 4M
    f16* w2T  = w1T  + (size_t)D * DFF;      // 4M
    f16* qk   = w2T  + (size_t)DFF * D;      // 16M ([8192][2048])
    f16* vT   = qk   + (size_t)NTOK * 2 * D; // 8M  ([1024][8192])
    float* sb = (float*)(vT + (size_t)D * NTOK);  // 16M fp32 (64 MB)
    f16* ph   = qk;                          // probs overwrite q|k (16M)
    f16* at   = xh;                          // attn overwrites xh
    f16* pj   = vT;                          // proj overwrites vT
    f16* hd   = (f16*)sb;                    // hidden overwrites scores

    dim3 blk(256);

    // casts / transposes
    cast_f16<<<dim3(NTOK * D / 1024), blk, 0, stream>>>(x, xh);
    transpose_cast<<<dim3(D / 64, D / 64), blk, 0, stream>>>(wq, wqkT, D, D);
    transpose_cast<<<dim3(D / 64, D / 64), blk, 0, stream>>>(wk, wqkT + (size_t)D * D, D, D);
    transpose_cast<<<dim3(D / 64, D / 64), blk, 0, stream>>>(wv, wvT, D, D);
    transpose_cast<<<dim3(D / 64, D / 64), blk, 0, stream>>>(wo, woT, D, D);
    transpose_cast<<<dim3(DFF / 64, D / 64), blk, 0, stream>>>(w1, w1T, D, DFF);
    transpose_cast<<<dim3(D / 64, DFF / 64), blk, 0, stream>>>(w2, w2T, DFF, D);

    // qk = xh @ wqkT'   [8192][2048]
    gemm_f16<0><<<dim3(NTOK / BM, 2 * D / BN, 1), blk, 0, stream>>>(
        xh, wqkT, nullptr, qk, D, D, D, 2 * D, 0, 0, 0);
    // vT = wvT @ xh'    [1024][8192]
    gemm_f16<0><<<dim3(D / BM, NTOK / BN, 1), blk, 0, stream>>>(
        wvT, xh, nullptr, vT, D, D, D, NTOK, 0, 0, 0);

    // scores[b] = q_b @ k_b'  fp32 [2048][2048] x4
    gemm_f16<2><<<dim3(S / BM, S / BN, Bb), blk, 0, stream>>>(
        qk, qk + D, nullptr, sb, D, 2 * D, 2 * D, S,
        (long long)S * 2 * D, (long long)S * 2 * D, (long long)S * S);

    // softmax -> fp16 probs (overwrites qk)
    softmax_f16<<<dim3(NTOK), blk, 0, stream>>>(sb, ph);

    // attn[b] = p_b @ (vT[:, b-slice])'   [2048][1024] x4
    gemm_f16<0><<<dim3(S / BM, D / BN, Bb), blk, 0, stream>>>(
        ph, vT, nullptr, at, S, S, NTOK, D,
        (long long)S * S, (long long)S, (long long)S * D);

    // proj = at @ woT'
    gemm_f16<0><<<dim3(NTOK / BM, D / BN, 1), blk, 0, stream>>>(
        at, woT, nullptr, pj, D, D, D, D, 0, 0, 0);

    // hidden = relu(pj @ w1T')   [8192][4096]
    gemm_f16<1><<<dim3(NTOK / BM, DFF / BN, 1), blk, 0, stream>>>(
        pj, w1T, nullptr, hd, D, D, D, DFF, 0, 0, 0);

    // out = hd @ w2T' + x   fp32 [8192][1024]
    gemm_f16<3><<<dim3(NTOK / BM, D / BN, 1), blk, 0, stream>>>(
        hd, w2T, x, out, DFF, DFF, DFF, D, 0, 0, 0);
}

// Round 4
// 464.806 us; speedup vs baseline: 7.1450x; 1.0802x over previous
//
#include <hip/hip_runtime.h>
#include <hip/hip_bf16.h>
#include <hip/hip_fp16.h>

// TinyTransformerBlock: B=4, S=2048, D=1024, DFF=4096, fp32 in/out.
// R4: XOR-swizzled LDS layout to kill 16-way bank conflicts on fragment reads.
// LDS slot (row, h) holds global k-half (h ^ (row&7)); global_load_lds writes
// stay linear (HW lane*16), reads spread across all 32 banks (2-way max = free).
//
// All GEMMs NT: C[M][N] = A[M][K] * Bt[N][K]^T, f16 MFMA 16x16x32, BK=64.

typedef _Float16 f16;
typedef __attribute__((ext_vector_type(8))) _Float16 f16x8;
typedef __attribute__((ext_vector_type(4))) _Float16 f16x4;
typedef __attribute__((ext_vector_type(4))) float f32x4;

#define BM 128
#define BN 128
#define BK 64

__device__ inline void gload16(const void* g, void* l) {
    __builtin_amdgcn_global_load_lds(
        (const __attribute__((address_space(1))) void*)g,
        (__attribute__((address_space(3))) void*)l, 16, 0, 0);
}

// EPI: 0 = f16 store, 1 = f16 relu store, 2 = f32 store, 3 = f32 + residual
// Grid: x = M-tile (fastest -> XCD-pinned A rows), y = N-tile, z = batch.
template<int EPI>
__global__ __launch_bounds__(256)
void gemm_f16(const f16* __restrict__ A, const f16* __restrict__ Bt,
              const float* __restrict__ Res, void* __restrict__ Cv,
              int K, int lda, int ldb, int ldc,
              long long sA, long long sB, long long sC)
{
    __shared__ f16 Ash[BM * BK];   // 16 KB
    __shared__ f16 Bsh[BN * BK];   // 16 KB

    const int t = threadIdx.x;
    const int z = blockIdx.z;
    A  += (size_t)z * sA;
    Bt += (size_t)z * sB;

    const int bm0 = blockIdx.x * BM;   // M-tile fastest
    const int bn0 = blockIdx.y * BN;

    const int lane = t & 63;
    const int wid  = t >> 6;            // wave 0..3
    const int quad = lane >> 4;
    const int m16  = lane & 15;
    const int wm = (wid & 1) * 64;
    const int wn = (wid >> 1) * 64;

    // staging: chunk c = i*256 + t -> LDS row r = c>>3 (128 B rows), LDS half
    // slot t&7. Source k-half is XOR-swizzled: kc = ((t&7) ^ (r&7)) * 8 f16.
    const int r0 = t >> 3;              // 0..31
    const int kc = ((t & 7) ^ (r0 & 7)) * 8;
    const char* gA[4]; const char* gB[4];
    #pragma unroll
    for (int i = 0; i < 4; ++i) {
        gA[i] = (const char*)(A  + (size_t)(bm0 + i * 32 + r0) * lda + kc);
        gB[i] = (const char*)(Bt + (size_t)(bn0 + i * 32 + r0) * ldb + kc);
    }
    char* lA = (char*)Ash + (wid << 10);   // wave-uniform base (+ lane*16 by HW)
    char* lB = (char*)Bsh + (wid << 10);

    f32x4 acc[4][4] = {};

    const int nk = K / BK;
    #define ISSUE(kt) do { const int ko = (kt) * 128;   \
        gload16(gA[0] + ko, lA);                        \
        gload16(gA[1] + ko, lA + 4096);                 \
        gload16(gA[2] + ko, lA + 8192);                 \
        gload16(gA[3] + ko, lA + 12288);                \
        gload16(gB[0] + ko, lB);                        \
        gload16(gB[1] + ko, lB + 4096);                 \
        gload16(gB[2] + ko, lB + 8192);                 \
        gload16(gB[3] + ko, lB + 12288); } while (0)

    const int swz = m16 & 7;            // row&7 for all this lane's fragment rows

    ISSUE(0);
    for (int kt = 0; kt < nk; ++kt) {
        __syncthreads();                       // tile kt resident (vmcnt drained)
        f16x8 af[2][4], bf[2][4];
        #pragma unroll
        for (int s = 0; s < 2; ++s)
            #pragma unroll
            for (int i = 0; i < 4; ++i) {
                const int ha = (((s << 2) | quad) ^ swz) * 8;  // swizzled k-half
                af[s][i] = *(const f16x8*)&Ash[(wm + i * 16 + m16) * BK + ha];
                bf[s][i] = *(const f16x8*)&Bsh[(wn + i * 16 + m16) * BK + ha];
            }
        __syncthreads();                       // all waves' ds_reads done
        if (kt + 1 < nk) ISSUE(kt + 1);        // prefetch overlaps MFMA
        #pragma unroll
        for (int s = 0; s < 2; ++s)
            #pragma unroll
            for (int i = 0; i < 4; ++i)
                #pragma unroll
                for (int j = 0; j < 4; ++j)
                    acc[i][j] = __builtin_amdgcn_mfma_f32_16x16x32_f16(
                                    af[s][i], bf[s][j], acc[i][j], 0, 0, 0);
    }
    #undef ISSUE

    // C/D layout: col = lane&15, row = quad*4 + reg
    if (EPI <= 1) {
        f16* C = (f16*)Cv + (size_t)z * sC;
        #pragma unroll
        for (int i = 0; i < 4; ++i)
            #pragma unroll
            for (int ri = 0; ri < 4; ++ri) {
                const size_t row = (size_t)(bm0 + wm + i * 16 + quad * 4 + ri);
                f16* cp = C + row * ldc + (bn0 + wn + m16);
                #pragma unroll
                for (int j = 0; j < 4; ++j) {
                    float v = acc[i][j][ri];
                    if (EPI == 1) v = fmaxf(v, 0.0f);
                    cp[j * 16] = (f16)v;
                }
            }
    } else {
        float* C = (float*)Cv + (size_t)z * sC;
        #pragma unroll
        for (int i = 0; i < 4; ++i)
            #pragma unroll
            for (int ri = 0; ri < 4; ++ri) {
                const size_t row = (size_t)(bm0 + wm + i * 16 + quad * 4 + ri);
                float* cp = C + row * ldc + (bn0 + wn + m16);
                const float* rp = (EPI == 3) ? Res + row * ldc + (bn0 + wn + m16)
                                             : nullptr;
                #pragma unroll
                for (int j = 0; j < 4; ++j) {
                    float v = acc[i][j][ri];
                    if (EPI == 3) v += rp[j * 16];
                    cp[j * 16] = v;
                }
            }
    }
}

// fp32 [R][C] -> fp16 [C][R]
__global__ __launch_bounds__(256)
void transpose_cast(const float* __restrict__ in, f16* __restrict__ out,
                    int R, int C)
{
    __shared__ float tile[64][65];
    const int c0 = blockIdx.x * 64, r0 = blockIdx.y * 64;
    const int tc = threadIdx.x & 63, tr = threadIdx.x >> 6;   // tr 0..3
    #pragma unroll
    for (int i = 0; i < 16; ++i)
        tile[tr + i * 4][tc] = in[(size_t)(r0 + tr + i * 4) * C + c0 + tc];
    __syncthreads();
    #pragma unroll
    for (int i = 0; i < 16; ++i)
        out[(size_t)(c0 + tr + i * 4) * R + r0 + tc] = (f16)tile[tc][tr + i * 4];
}

__global__ __launch_bounds__(256)
void cast_f16(const float* __restrict__ in, f16* __restrict__ out)
{
    const size_t i = ((size_t)blockIdx.x * 256 + threadIdx.x) * 4;
    float4 v = *(const float4*)(in + i);
    f16x4 o; o.x = (f16)v.x; o.y = (f16)v.y; o.z = (f16)v.z; o.w = (f16)v.w;
    *(f16x4*)(out + i) = o;
}

// row softmax over 2048 fp32 -> fp16
__global__ __launch_bounds__(256)
void softmax_f16(const float* __restrict__ S, f16* __restrict__ P)
{
    __shared__ float red[256];
    const float* p = S + (size_t)blockIdx.x * 2048;
    f16* q = P + (size_t)blockIdx.x * 2048;
    const int t = threadIdx.x;

    float4 u0 = *(const float4*)(p + t * 4);
    float4 u1 = *(const float4*)(p + 1024 + t * 4);

    float m = fmaxf(fmaxf(fmaxf(u0.x, u0.y), fmaxf(u0.z, u0.w)),
                    fmaxf(fmaxf(u1.x, u1.y), fmaxf(u1.z, u1.w)));
    red[t] = m;
    __syncthreads();
    #pragma unroll
    for (int s = 128; s > 0; s >>= 1) {
        if (t < s) red[t] = fmaxf(red[t], red[t + s]);
        __syncthreads();
    }
    const float rowmax = red[0];
    __syncthreads();

    u0.x = __expf(u0.x - rowmax); u0.y = __expf(u0.y - rowmax);
    u0.z = __expf(u0.z - rowmax); u0.w = __expf(u0.w - rowmax);
    u1.x = __expf(u1.x - rowmax); u1.y = __expf(u1.y - rowmax);
    u1.z = __expf(u1.z - rowmax); u1.w = __expf(u1.w - rowmax);

    red[t] = (u0.x + u0.y + u0.z + u0.w) + (u1.x + u1.y + u1.z + u1.w);
    __syncthreads();
    #pragma unroll
    for (int s = 128; s > 0; s >>= 1) {
        if (t < s) red[t] += red[t + s];
        __syncthreads();
    }
    const float inv = 1.0f / red[0];

    f16x4 o0, o1;
    o0.x = (f16)(u0.x * inv); o0.y = (f16)(u0.y * inv);
    o0.z = (f16)(u0.z * inv); o0.w = (f16)(u0.w * inv);
    o1.x = (f16)(u1.x * inv); o1.y = (f16)(u1.y * inv);
    o1.z = (f16)(u1.z * inv); o1.w = (f16)(u1.w * inv);
    *(f16x4*)(q + t * 4)        = o0;
    *(f16x4*)(q + 1024 + t * 4) = o1;
}

extern "C" void kernel_launch(void* const* d_in, const int* in_sizes, int n_in,
                              void* d_out, int out_size, void* d_ws, size_t ws_size,
                              hipStream_t stream)
{
    const float* x  = (const float*)d_in[0];
    const float* wq = (const float*)d_in[1];
    const float* wk = (const float*)d_in[2];
    const float* wv = (const float*)d_in[3];
    const float* wo = (const float*)d_in[4];
    const float* w1 = (const float*)d_in[5];
    const float* w2 = (const float*)d_in[6];
    float* out = (float*)d_out;

    const int S = 2048, D = 1024, DFF = 4096, Bb = 4;
    const int NTOK = Bb * S;  // 8192

    // workspace (halves unless noted); total 152 MB
    f16* W    = (f16*)d_ws;
    f16* xh   = W;                           // 8M
    f16* wqkT = xh   + (size_t)NTOK * D;     // 2M  ([2048][1024]: wqT | wkT)
    f16* wvT  = wqkT + (size_t)2 * D * D;    // 1M
    f16* woT  = wvT  + (size_t)D * D;        // 1M
    f16* w1T  = woT  + (size_t)D * D;        // 4M
    f16* w2T  = w1T  + (size_t)D * DFF;      // 4M
    f16* qk   = w2T  + (size_t)DFF * D;      // 16M ([8192][2048])
    f16* vT   = qk   + (size_t)NTOK * 2 * D; // 8M  ([1024][8192])
    float* sb = (float*)(vT + (size_t)D * NTOK);  // 16M fp32 (64 MB)
    f16* ph   = qk;                          // probs overwrite q|k (16M)
    f16* at   = xh;                          // attn overwrites xh
    f16* pj   = vT;                          // proj overwrites vT
    f16* hd   = (f16*)sb;                    // hidden overwrites scores

    dim3 blk(256);

    // casts / transposes
    cast_f16<<<dim3(NTOK * D / 1024), blk, 0, stream>>>(x, xh);
    transpose_cast<<<dim3(D / 64, D / 64), blk, 0, stream>>>(wq, wqkT, D, D);
    transpose_cast<<<dim3(D / 64, D / 64), blk, 0, stream>>>(wk, wqkT + (size_t)D * D, D, D);
    transpose_cast<<<dim3(D / 64, D / 64), blk, 0, stream>>>(wv, wvT, D, D);
    transpose_cast<<<dim3(D / 64, D / 64), blk, 0, stream>>>(wo, woT, D, D);
    transpose_cast<<<dim3(DFF / 64, D / 64), blk, 0, stream>>>(w1, w1T, D, DFF);
    transpose_cast<<<dim3(D / 64, DFF / 64), blk, 0, stream>>>(w2, w2T, DFF, D);

    // qk = xh @ wqkT'   [8192][2048]
    gemm_f16<0><<<dim3(NTOK / BM, 2 * D / BN, 1), blk, 0, stream>>>(
        xh, wqkT, nullptr, qk, D, D, D, 2 * D, 0, 0, 0);
    // vT = wvT @ xh'    [1024][8192]
    gemm_f16<0><<<dim3(D / BM, NTOK / BN, 1), blk, 0, stream>>>(
        wvT, xh, nullptr, vT, D, D, D, NTOK, 0, 0, 0);

    // scores[b] = q_b @ k_b'  fp32 [2048][2048] x4
    gemm_f16<2><<<dim3(S / BM, S / BN, Bb), blk, 0, stream>>>(
        qk, qk + D, nullptr, sb, D, 2 * D, 2 * D, S,
        (long long)S * 2 * D, (long long)S * 2 * D, (long long)S * S);

    // softmax -> fp16 probs (overwrites qk)
    softmax_f16<<<dim3(NTOK), blk, 0, stream>>>(sb, ph);

    // attn[b] = p_b @ (vT[:, b-slice])'   [2048][1024] x4
    gemm_f16<0><<<dim3(S / BM, D / BN, Bb), blk, 0, stream>>>(
        ph, vT, nullptr, at, S, S, NTOK, D,
        (long long)S * S, (long long)S, (long long)S * D);

    // proj = at @ woT'
    gemm_f16<0><<<dim3(NTOK / BM, D / BN, 1), blk, 0, stream>>>(
        at, woT, nullptr, pj, D, D, D, D, 0, 0, 0);

    // hidden = relu(pj @ w1T')   [8192][4096]
    gemm_f16<1><<<dim3(NTOK / BM, DFF / BN, 1), blk, 0, stream>>>(
        pj, w1T, nullptr, hd, D, D, D, DFF, 0, 0, 0);

    // out = hd @ w2T' + x   fp32 [8192][1024]
    gemm_f16<3><<<dim3(NTOK / BM, D / BN, 1), blk, 0, stream>>>(
        hd, w2T, x, out, DFF, DFF, DFF, D, 0, 0, 0);
}